// Round 6
// baseline (119.525 us; speedup 1.0000x reference)
//
#include <hip/hip_runtime.h>
#include <hip/hip_bf16.h>

// Problem constants: B=64, N=32, S=256, D=128
#define B_SZ 64

typedef __attribute__((ext_vector_type(8))) short bf16x8;
typedef __attribute__((ext_vector_type(4))) float f32x4;

static __device__ __forceinline__ unsigned short f2bf(float f) {
    __hip_bfloat16 h = __float2bfloat16(f);
    return *reinterpret_cast<unsigned short*>(&h);
}

// Load 8 consecutive fp32 (32 B), convert to one bf16x8 fragment.
// MFMA A and B fragments are k-contiguous per lane, so fragments load DIRECTLY
// from the row-major fp32 inputs — no transpose/permute pass needed at all.
static __device__ __forceinline__ bf16x8 cvt_frag(const float* __restrict__ src) {
    float4 a = reinterpret_cast<const float4*>(src)[0];
    float4 b = reinterpret_cast<const float4*>(src)[1];
    union { bf16x8 v; unsigned short u[8]; } t;
    t.u[0] = f2bf(a.x); t.u[1] = f2bf(a.y); t.u[2] = f2bf(a.z); t.u[3] = f2bf(a.w);
    t.u[4] = f2bf(b.x); t.u[5] = f2bf(b.y); t.u[6] = f2bf(b.z); t.u[7] = f2bf(b.w);
    return t.v;
}

#define MFMA(A, Bv, C) __builtin_amdgcn_mfma_f32_16x16x32_bf16(A, Bv, C, 0, 0, 0)

// Direct-load B-in-register MaxSim. No doc LDS, no cvt pass, no workspace
// round-trip. LDS = 4 KiB wred only -> 3 blocks/CU, 3 waves/SIMD.
// wg < 512 (pos): x = wg&7 (XCD under default wg%8 placement), i = wg>>3;
//   column c = x*8 + (i&7) -> all 8 blocks of column c land on XCD x, so the
//   128 KiB doc tile is read once from HBM/L3 then L2-hit by the other 7.
//   Block covers b in [ (i>>3)*8, +8 ).
// wg >= 512 (neg): pair b = wg-512, doc nd[b], single-b loop, score slot 64.
//
// Fragment indexing (identical to the harness-verified R3 DP/QP layout):
//   Bv[kk][nt] lane l = doc[s = wave*64 + nt*16 + (l&15)][k = kk*32+(l>>4)*8 ..+7]
//   Af[kk][mt] lane l = q[b][n = mt*16 + (l&15)]          [k = kk*32+(l>>4)*8 ..+7]
// Each wave-load = 16 rows x 128 contiguous B; sweeping kk covers rows densely.
__global__ __launch_bounds__(256, 3) void maxsim_direct(const float* __restrict__ q,
                                                        const float* __restrict__ dd,
                                                        const float* __restrict__ nd,
                                                        float* __restrict__ scores) {
    const int wg  = blockIdx.x;
    const int tid = threadIdx.x;
    const int wave = tid >> 6, lane = tid & 63;
    const int l15 = lane & 15, lhi = lane >> 4;

    __shared__ float wred[8][4][4][8];   // [bi][wave][lhi][mt*4+r]

    int c, b0, nb;
    const float* docp;
    if (wg < 512) {
        const int x = wg & 7, i = wg >> 3;
        c   = x * 8 + (i & 7);
        b0  = (i >> 3) * 8;
        nb  = 8;
        docp = dd + (size_t)c * 32768;
    } else {
        b0 = wg - 512; c = 64; nb = 1;
        docp = nd + (size_t)b0 * 32768;
    }

    // ---- stage this wave's s-chunk (ch = wave) straight into registers ----
    bf16x8 Bv[4][4];                     // [kk][nt]
    {
        const float* base = docp + (size_t)(wave * 64 + l15) * 128 + lhi * 8;
        #pragma unroll
        for (int kk = 0; kk < 4; ++kk)
            #pragma unroll
            for (int nt = 0; nt < 4; ++nt)
                Bv[kk][nt] = cvt_frag(base + nt * 16 * 128 + kk * 32);
    }

    // ---- loop over batches: direct A-frag loads, 32 MFMAs, fold, stash ----
    const float* qbase = q + (size_t)b0 * 4096 + (size_t)l15 * 128 + lhi * 8;
    for (int bi = 0; bi < nb; ++bi) {
        bf16x8 Af[4][2];
        const float* qb = qbase + (size_t)bi * 4096;
        #pragma unroll
        for (int kk = 0; kk < 4; ++kk) {
            Af[kk][0] = cvt_frag(qb + kk * 32);
            Af[kk][1] = cvt_frag(qb + 16 * 128 + kk * 32);
        }
        f32x4 acc[2][4] = {};            // [mt][nt]
        #pragma unroll
        for (int kk = 0; kk < 4; ++kk)
            #pragma unroll
            for (int nt = 0; nt < 4; ++nt) {
                acc[0][nt] = MFMA(Af[kk][0], Bv[kk][nt], acc[0][nt]);
                acc[1][nt] = MFMA(Af[kk][1], Bv[kk][nt], acc[1][nt]);
            }
        // max over this wave's 64 docs; butterfly over l15 -> per-row chunk max
        #pragma unroll
        for (int mt = 0; mt < 2; ++mt)
            #pragma unroll
            for (int r = 0; r < 4; ++r) {
                float m = fmaxf(fmaxf(acc[mt][0][r], acc[mt][1][r]),
                                fmaxf(acc[mt][2][r], acc[mt][3][r]));
                m = fmaxf(m, __shfl_xor(m, 1, 64));
                m = fmaxf(m, __shfl_xor(m, 2, 64));
                m = fmaxf(m, __shfl_xor(m, 4, 64));
                m = fmaxf(m, __shfl_xor(m, 8, 64));
                if (l15 == 0) wred[bi][wave][lhi][mt * 4 + r] = m;
                // row n = mt*16 + lhi*4 + r
            }
    }
    __syncthreads();

    // ---- final: max over the 4 s-chunks, then sum over the 32 query rows ----
    if (tid < nb * 32) {
        const int bi = tid >> 5, n = tid & 31;
        const int slot = (n >> 4) * 4 + (n & 3);   // mt*4 + r
        const int lh   = (n >> 2) & 3;
        float m = fmaxf(fmaxf(wred[bi][0][lh][slot], wred[bi][1][lh][slot]),
                        fmaxf(wred[bi][2][lh][slot], wred[bi][3][lh][slot]));
        m += __shfl_xor(m, 1, 32);
        m += __shfl_xor(m, 2, 32);
        m += __shfl_xor(m, 4, 32);
        m += __shfl_xor(m, 8, 32);
        m += __shfl_xor(m, 16, 32);
        if (n == 0) scores[(size_t)(b0 + bi) * 65 + c] = m;  // c==64 -> neg slot
    }
}

static __device__ __forceinline__ float softplusf(float x) {
    return fmaxf(x, 0.0f) + log1pf(expf(-fabsf(x)));
}

__global__ __launch_bounds__(64) void loss_kernel(const float* __restrict__ scores,
                                                  float* __restrict__ out) {
    const int b = threadIdx.x;           // 64 threads = 1 wave
    const float* row = scores + b * 65;
    const float pos  = row[b];
    const float negq = row[64];
    float nib = -1e30f;
    #pragma unroll
    for (int c = 0; c < B_SZ; ++c) {
        float v = row[c] - ((c == b) ? 1000000.0f : 0.0f);
        nib = fmaxf(nib, v);
    }
    float t = softplusf(negq - pos) + softplusf(nib - pos);
    t += __shfl_xor(t, 1, 64);
    t += __shfl_xor(t, 2, 64);
    t += __shfl_xor(t, 4, 64);
    t += __shfl_xor(t, 8, 64);
    t += __shfl_xor(t, 16, 64);
    t += __shfl_xor(t, 32, 64);
    if (b == 0) out[0] = t * (0.5f / 64.0f);
}

extern "C" void kernel_launch(void* const* d_in, const int* in_sizes, int n_in,
                              void* d_out, int out_size, void* d_ws, size_t ws_size,
                              hipStream_t stream) {
    const float* q  = (const float*)d_in[0];   // (64, 32, 128)
    const float* dd = (const float*)d_in[1];   // (64, 256, 128)
    const float* nd = (const float*)d_in[2];   // (64, 256, 128)
    float* out = (float*)d_out;

    // Workspace: scores (64 x 65 f32) only.
    float* scores = (float*)d_ws;

    maxsim_direct<<<512 + B_SZ, 256, 0, stream>>>(q, dd, nd, scores);
    loss_kernel<<<1, 64, 0, stream>>>(scores, out);
}